// Round 5
// baseline (551.919 us; speedup 1.0000x reference)
//
#include <hip/hip_runtime.h>
#include <hip/hip_bf16.h>

#define NB   16
#define SQL  2048
#define SKL  2048
#define DKL  64
#define DVL  64
#define NE   (NB * SQL * DKL)   /* 2,097,152 elems per tensor */

typedef __attribute__((ext_vector_type(8))) short short8;
typedef __attribute__((ext_vector_type(4))) short s16x4;
typedef __attribute__((ext_vector_type(4))) float f32x4;

#define PST 56   // P LDS row stride (elems)

#define SCALE_LOG2E 0.1803368801111204f  /* (1/sqrt(64)) * log2(e) */
#define EXP2F(x) __builtin_amdgcn_exp2f(x)

__device__ __forceinline__ short f2bf(float x) {  // rne f32 -> bf16 bits
    unsigned u = __builtin_bit_cast(unsigned, x);
    u = (u + 0x7fffu + ((u >> 16) & 1u)) >> 16;
    return (short)u;
}
__device__ __forceinline__ float bf2f(short s) {
    return __builtin_bit_cast(float, ((unsigned)(unsigned short)s) << 16);
}

// ---------- prep: split Q,K into bf16 hi/lo ----------
__global__ __launch_bounds__(256)
void prep(const float* __restrict__ Q, const float* __restrict__ K,
          short* __restrict__ ws)
{
    short* qhi = ws;
    short* qlo = ws + (size_t)NE;
    short* khi = ws + (size_t)2 * NE;
    short* klo = ws + (size_t)3 * NE;

    size_t i4 = ((size_t)blockIdx.x * 256 + threadIdx.x) * 4;
    if (i4 >= NE) return;

    f32x4 q = *(const f32x4*)(Q + i4);
    f32x4 k = *(const f32x4*)(K + i4);
    s16x4 qh, ql, kh, kl;
    #pragma unroll
    for (int j = 0; j < 4; j++) {
        qh[j] = f2bf(q[j]);  ql[j] = f2bf(q[j] - bf2f(qh[j]));
        kh[j] = f2bf(k[j]);  kl[j] = f2bf(k[j] - bf2f(kh[j]));
    }
    *(s16x4*)(qhi + i4) = qh;
    *(s16x4*)(qlo + i4) = ql;
    *(s16x4*)(khi + i4) = kh;
    *(s16x4*)(klo + i4) = kl;
}

// ---------- vtrans: V fp32 [b][k][v] -> Vt bf16 [b][v][k] ----------
__global__ __launch_bounds__(256)
void vtrans(const float* __restrict__ V, short* __restrict__ vt)
{
    const int b  = blockIdx.x >> 5;       // 16 batches
    const int kt = blockIdx.x & 31;       // 32 k-tiles of 64
    const int v  = threadIdx.x & 63;
    const int kg = (threadIdx.x >> 6) * 16;

    const float* src = V + ((size_t)b * SKL + kt * 64 + kg) * DVL + v;
    short* dst = vt + (size_t)b * DVL * SKL + (size_t)v * SKL + kt * 64 + kg;

    short8 lo8, hi8;
    #pragma unroll
    for (int j = 0; j < 8; j++) lo8[j] = f2bf(src[(size_t)j * DVL]);
    #pragma unroll
    for (int j = 0; j < 8; j++) hi8[j] = f2bf(src[(size_t)(j + 8) * DVL]);
    *(short8*)dst = lo8;
    *(short8*)(dst + 8) = hi8;
}

// s-tiles for 32 keys: s = Qhi*Khi + (Qlo*Khi + Qhi*Klo), split into
// independent chains (len 2 + len 4) for MFMA latency hiding.
__device__ __forceinline__ void qk_tiles(const short* __restrict__ khi,
                                         const short* __restrict__ klo, int kb,
                                         int l15, int quad,
                                         short8 qa0h, short8 qa1h,
                                         short8 qa0l, short8 qa1l,
                                         f32x4& s0, f32x4& s1) {
    size_t o0 = (size_t)(kb + l15) * DKL + quad * 8;
    size_t o1 = o0 + (size_t)16 * DKL;
    short8 h0l = *(const short8*)(khi + o0);
    short8 h0h = *(const short8*)(khi + o0 + 32);
    short8 h1l = *(const short8*)(khi + o1);
    short8 h1h = *(const short8*)(khi + o1 + 32);
    short8 l0l = *(const short8*)(klo + o0);
    short8 l0h = *(const short8*)(klo + o0 + 32);
    short8 l1l = *(const short8*)(klo + o1);
    short8 l1h = *(const short8*)(klo + o1 + 32);
    f32x4 z = {0.f, 0.f, 0.f, 0.f};
    f32x4 a0 = __builtin_amdgcn_mfma_f32_16x16x32_bf16(qa0h, h0l, z, 0, 0, 0);
    a0 = __builtin_amdgcn_mfma_f32_16x16x32_bf16(qa1h, h0h, a0, 0, 0, 0);
    f32x4 b0 = __builtin_amdgcn_mfma_f32_16x16x32_bf16(qa0l, h0l, z, 0, 0, 0);
    b0 = __builtin_amdgcn_mfma_f32_16x16x32_bf16(qa1l, h0h, b0, 0, 0, 0);
    b0 = __builtin_amdgcn_mfma_f32_16x16x32_bf16(qa0h, l0l, b0, 0, 0, 0);
    b0 = __builtin_amdgcn_mfma_f32_16x16x32_bf16(qa1h, l0h, b0, 0, 0, 0);
    f32x4 a1 = __builtin_amdgcn_mfma_f32_16x16x32_bf16(qa0h, h1l, z, 0, 0, 0);
    a1 = __builtin_amdgcn_mfma_f32_16x16x32_bf16(qa1h, h1h, a1, 0, 0, 0);
    f32x4 b1 = __builtin_amdgcn_mfma_f32_16x16x32_bf16(qa0l, h1l, z, 0, 0, 0);
    b1 = __builtin_amdgcn_mfma_f32_16x16x32_bf16(qa1l, h1h, b1, 0, 0, 0);
    b1 = __builtin_amdgcn_mfma_f32_16x16x32_bf16(qa0h, l1l, b1, 0, 0, 0);
    b1 = __builtin_amdgcn_mfma_f32_16x16x32_bf16(qa1h, l1h, b1, 0, 0, 0);
    s0 = a0 + b0;
    s1 = a1 + b1;
}

// Block: 256 threads = 4 waves. wave = qt(2) x kh(2): 2 q-tiles of 16,
// K split in halves. Grid: 16 batches x 64 q-blocks of 32 = 1024 blocks.
__global__ __launch_bounds__(256, 4)
void attn_fwd(const short* __restrict__ ws, const int* __restrict__ mask,
              float* __restrict__ out, float* __restrict__ attn)
{
    __shared__ float s_l[2][16][2];        // partial softmax denominators
    __shared__ float s_o[2][16][64];       // O combine buffer (8 KB)
    __shared__ short s_p[4 * 16 * PST];    // per-wave P tile (7 KB)

    const int tid  = threadIdx.x;
    const int wave = tid >> 6;
    const int l15  = tid & 15;
    const int quad = (tid & 63) >> 4;
    const int qt   = wave & 1;
    const int kh   = wave >> 1;

    const int b  = blockIdx.x >> 6;
    const int qb = (blockIdx.x & 63) * 32 + qt * 16;  // wave's 16-query tile
    const int k0 = kh * (SKL / 2);

    const short* qhi  = ws + (size_t)(b * SQL + qb) * DKL;
    const short* qlo  = qhi + (size_t)NE;
    const short* khiB = ws + (size_t)2 * NE + (size_t)b * SKL * DKL;
    const short* kloB = khiB + (size_t)NE;
    const short* vtB  = ws + (size_t)4 * NE + (size_t)b * DVL * SKL;
    const int*  maskB = mask + b * SKL;

    short8 qa0h = *(const short8*)(qhi + (size_t)l15 * DKL + quad * 8);
    short8 qa1h = *(const short8*)(qhi + (size_t)l15 * DKL + 32 + quad * 8);
    short8 qa0l = *(const short8*)(qlo + (size_t)l15 * DKL + quad * 8);
    short8 qa1l = *(const short8*)(qlo + (size_t)l15 * DKL + 32 + quad * 8);

    // ---------- sweep 1: partial denominators over this wave's K-half ----------
    float lsum[4] = {0.f, 0.f, 0.f, 0.f};
    #pragma unroll 2
    for (int kb = k0; kb < k0 + SKL / 2; kb += 32) {
        f32x4 s0, s1;
        qk_tiles(khiB, kloB, kb, l15, quad, qa0h, qa1h, qa0l, qa1l, s0, s1);
        float bias0 = maskB[kb + l15]      ? 0.0f : -1e9f;
        float bias1 = maskB[kb + 16 + l15] ? 0.0f : -1e9f;
        #pragma unroll
        for (int r = 0; r < 4; r++) {
            lsum[r] += EXP2F(fmaf(s0[r], SCALE_LOG2E, bias0));
            lsum[r] += EXP2F(fmaf(s1[r], SCALE_LOG2E, bias1));
        }
    }
    #pragma unroll
    for (int off = 1; off <= 8; off <<= 1) {
        #pragma unroll
        for (int r = 0; r < 4; r++)
            lsum[r] += __shfl_xor(lsum[r], off, 64);
    }
    if (l15 == 0) {
        #pragma unroll
        for (int r = 0; r < 4; r++)
            s_l[qt][quad * 4 + r][kh] = lsum[r];
    }
    __syncthreads();
    float inv_l[4];
    #pragma unroll
    for (int r = 0; r < 4; r++)
        inv_l[r] = 1.0f / (s_l[qt][quad * 4 + r][0] + s_l[qt][quad * 4 + r][1]);

    // ---------- sweep 2: attn write + partial P.V (no barriers in loop) ----------
    f32x4 acc[4];
    #pragma unroll
    for (int vt = 0; vt < 4; vt++) { f32x4 z = {0.f,0.f,0.f,0.f}; acc[vt] = z; }

    short* pw = s_p + wave * 16 * PST;

    for (int kb = k0; kb < k0 + SKL / 2; kb += 32) {
        f32x4 s0, s1;
        qk_tiles(khiB, kloB, kb, l15, quad, qa0h, qa1h, qa0l, qa1l, s0, s1);
        float bias0 = maskB[kb + l15]      ? 0.0f : -1e9f;
        float bias1 = maskB[kb + 16 + l15] ? 0.0f : -1e9f;

        const size_t arow = (size_t)(b * SQL + qb + quad * 4) * SKL + kb;
        #pragma unroll
        for (int r = 0; r < 4; r++) {
            float p0 = EXP2F(fmaf(s0[r], SCALE_LOG2E, bias0)) * inv_l[r];
            float p1 = EXP2F(fmaf(s1[r], SCALE_LOG2E, bias1)) * inv_l[r];
            attn[arow + (size_t)r * SKL + l15]      = p0;   // fp32 attn output
            attn[arow + (size_t)r * SKL + 16 + l15] = p1;
            pw[(quad * 4 + r) * PST + l15]      = f2bf(p0); // C-layout -> LDS
            pw[(quad * 4 + r) * PST + 16 + l15] = f2bf(p1);
        }

        short8 pa = *(const short8*)(pw + l15 * PST + quad * 8);  // A-layout
        #pragma unroll
        for (int vt = 0; vt < 4; vt++) {
            short8 bvv = *(const short8*)(vtB + (size_t)(vt * 16 + l15) * SKL + kb + quad * 8);
            acc[vt] = __builtin_amdgcn_mfma_f32_16x16x32_bf16(pa, bvv, acc[vt], 0, 0, 0);
        }
    }

    // ---------- combine K-halves, write O ----------
    if (kh == 1) {
        #pragma unroll
        for (int vt = 0; vt < 4; vt++)
            #pragma unroll
            for (int r = 0; r < 4; r++)
                s_o[qt][quad * 4 + r][vt * 16 + l15] = acc[vt][r];
    }
    __syncthreads();
    if (kh == 0) {
        #pragma unroll
        for (int vt = 0; vt < 4; vt++)
            #pragma unroll
            for (int r = 0; r < 4; r++)
                out[(size_t)(b * SQL + qb + quad * 4 + r) * DVL + vt * 16 + l15] =
                    acc[vt][r] + s_o[qt][quad * 4 + r][vt * 16 + l15];
    }
}

extern "C" void kernel_launch(void* const* d_in, const int* in_sizes, int n_in,
                              void* d_out, int out_size, void* d_ws, size_t ws_size,
                              hipStream_t stream) {
    const float* Q    = (const float*)d_in[0];
    const float* K    = (const float*)d_in[1];
    const float* V    = (const float*)d_in[2];
    const int*   mask = (const int*)d_in[3];
    float* out  = (float*)d_out;
    float* attn = out + (size_t)NB * SQL * DVL;  // tuple order: (output, attn)
    short* ws   = (short*)d_ws;                  // 5*NE shorts = 20 MB

    prep<<<dim3(NE / (256 * 4)), dim3(256), 0, stream>>>(Q, K, ws);
    vtrans<<<dim3(NB * (SKL / 64)), dim3(256), 0, stream>>>(V, ws + (size_t)4 * NE);
    attn_fwd<<<dim3(NB * (SQL / 32)), dim3(256), 0, stream>>>(ws, mask, out, attn);
}